// Round 2
// baseline (190.731 us; speedup 1.0000x reference)
//
#include <hip/hip_runtime.h>

// Segment-mean pooling: x [N,128] fp32, batch [N] sorted int -> out [1024,128] fp32.
// 3-phase deterministic: A) segment bounds via binary search, B) partial sums
// (4 blocks/segment for scheduling granularity), C) combine + divide.

#define NSEG  1024
#define DDIM  128
#define D4    32          // DDIM / 4 floats per float4
#define SPLIT 4
#define NB    (NSEG * SPLIT)

__device__ __forceinline__ int bload(const int* __restrict__ b, long i, bool is64) {
    // int64 little-endian: value in even i32 word (values < 1024 => hi word 0)
    return is64 ? b[i << 1] : b[i];
}

// ---------- Phase A: bounds[s] = lower_bound(batch, s), bounds[NSEG] = N ----
__global__ __launch_bounds__(256) void bounds_kernel(
    const int* __restrict__ b32, int* __restrict__ bounds, long N)
{
    const int gid = blockIdx.x * 256 + threadIdx.x;   // [0, NSEG)
    const bool is64 = (b32[N - 1] == 0);  // hi-word of last int64 elem, else last value ~1023
    if (gid == 0) bounds[0] = 0;
    const int v = gid + 1;                 // search lower_bound(v), v in [1, NSEG]
    long lo = 0, hi = N;
    while (lo < hi) {
        long mid = (lo + hi) >> 1;
        if (bload(b32, mid, is64) < v) lo = mid + 1; else hi = mid;
    }
    bounds[v] = (int)lo;
}

// ---------- Phase B: partial sums, one block per (segment, quarter) ---------
__global__ __launch_bounds__(256) void partial_kernel(
    const float4* __restrict__ x4, const int* __restrict__ bounds,
    float4* __restrict__ part)
{
    const int bid = blockIdx.x;
    const int seg = bid >> 2;
    const int q   = bid & 3;
    const int t   = threadIdx.x;

    const int start = bounds[seg];
    const int len   = bounds[seg + 1] - start;
    const int p0 = start + (int)(((long)len * q)       >> 2);
    const int p1 = start + (int)(((long)len * (q + 1)) >> 2);

    const int c = t & 31;   // float4 column
    const int r = t >> 5;   // row offset within group of 8

    float4 a0 = {0.f,0.f,0.f,0.f}, a1 = {0.f,0.f,0.f,0.f};
    float4 a2 = {0.f,0.f,0.f,0.f}, a3 = {0.f,0.f,0.f,0.f};

    int row = p0 + r;
    for (; row + 24 < p1; row += 32) {
        float4 v0 = x4[(long)(row     ) * D4 + c];
        float4 v1 = x4[(long)(row +  8) * D4 + c];
        float4 v2 = x4[(long)(row + 16) * D4 + c];
        float4 v3 = x4[(long)(row + 24) * D4 + c];
        a0.x += v0.x; a0.y += v0.y; a0.z += v0.z; a0.w += v0.w;
        a1.x += v1.x; a1.y += v1.y; a1.z += v1.z; a1.w += v1.w;
        a2.x += v2.x; a2.y += v2.y; a2.z += v2.z; a2.w += v2.w;
        a3.x += v3.x; a3.y += v3.y; a3.z += v3.z; a3.w += v3.w;
    }
    for (; row < p1; row += 8) {
        float4 v = x4[(long)row * D4 + c];
        a0.x += v.x; a0.y += v.y; a0.z += v.z; a0.w += v.w;
    }
    a0.x += a1.x + a2.x + a3.x;
    a0.y += a1.y + a2.y + a3.y;
    a0.z += a1.z + a2.z + a3.z;
    a0.w += a1.w + a2.w + a3.w;

    __shared__ float4 red[256];
    red[t] = a0;
    __syncthreads();

    if (t < 32) {
        float4 s = red[t];
#pragma unroll
        for (int rr = 1; rr < 8; ++rr) {
            float4 v = red[t + 32 * rr];
            s.x += v.x; s.y += v.y; s.z += v.z; s.w += v.w;
        }
        part[(long)bid * D4 + t] = s;
    }
}

// ---------- Phase C: out[s][d] = (sum of 4 partials) / count ----------------
__global__ __launch_bounds__(256) void combine_kernel(
    const float4* __restrict__ part, const int* __restrict__ bounds,
    float4* __restrict__ out4)
{
    const int idx = blockIdx.x * 256 + threadIdx.x;   // [0, NSEG*32)
    const int s = idx >> 5;
    const int c = idx & 31;

    float4 a = part[(long)(s * 4 + 0) * D4 + c];
    float4 b = part[(long)(s * 4 + 1) * D4 + c];
    float4 d = part[(long)(s * 4 + 2) * D4 + c];
    float4 e = part[(long)(s * 4 + 3) * D4 + c];
    a.x += b.x + d.x + e.x;
    a.y += b.y + d.y + e.y;
    a.z += b.z + d.z + e.z;
    a.w += b.w + d.w + e.w;

    const int cnt = bounds[s + 1] - bounds[s];
    const float inv = (cnt > 0) ? 1.0f / (float)cnt : 0.0f;
    a.x *= inv; a.y *= inv; a.z *= inv; a.w *= inv;
    out4[idx] = a;
}

// ---------- Fallback: original single-kernel path (small ws) ----------------
__global__ __launch_bounds__(256) void seg_mean_kernel(
    const float4* __restrict__ x4, const int* __restrict__ b32,
    float4* __restrict__ out4, long N)
{
    const int seg = blockIdx.x;
    const int t   = threadIdx.x;
    const bool is64 = (b32[N - 1] == 0);

    long lo = 0, hi = N;
    while (lo < hi) { long mid = (lo + hi) >> 1; if (bload(b32, mid, is64) < seg) lo = mid + 1; else hi = mid; }
    const long start = lo;
    hi = N;
    while (lo < hi) { long mid = (lo + hi) >> 1; if (bload(b32, mid, is64) <= seg) lo = mid + 1; else hi = mid; }
    const long end = lo;
    const long cnt = end - start;

    const int c = t & 31, r = t >> 5;
    float4 a0 = {0.f,0.f,0.f,0.f}, a1 = {0.f,0.f,0.f,0.f};
    float4 a2 = {0.f,0.f,0.f,0.f}, a3 = {0.f,0.f,0.f,0.f};

    long row = start + r;
    for (; row + 24 < end; row += 32) {
        float4 v0 = x4[(row      ) * D4 + c];
        float4 v1 = x4[(row +  8 ) * D4 + c];
        float4 v2 = x4[(row + 16 ) * D4 + c];
        float4 v3 = x4[(row + 24 ) * D4 + c];
        a0.x += v0.x; a0.y += v0.y; a0.z += v0.z; a0.w += v0.w;
        a1.x += v1.x; a1.y += v1.y; a1.z += v1.z; a1.w += v1.w;
        a2.x += v2.x; a2.y += v2.y; a2.z += v2.z; a2.w += v2.w;
        a3.x += v3.x; a3.y += v3.y; a3.z += v3.z; a3.w += v3.w;
    }
    for (; row < end; row += 8) {
        float4 v = x4[row * D4 + c];
        a0.x += v.x; a0.y += v.y; a0.z += v.z; a0.w += v.w;
    }
    a0.x += a1.x + a2.x + a3.x;
    a0.y += a1.y + a2.y + a3.y;
    a0.z += a1.z + a2.z + a3.z;
    a0.w += a1.w + a2.w + a3.w;

    __shared__ float4 red[256];
    red[t] = a0;
    __syncthreads();

    if (t < 32) {
        float4 s = red[t];
#pragma unroll
        for (int rr = 1; rr < 8; ++rr) {
            float4 v = red[t + 32 * rr];
            s.x += v.x; s.y += v.y; s.z += v.z; s.w += v.w;
        }
        const float inv = (cnt > 0) ? 1.0f / (float)cnt : 0.0f;
        s.x *= inv; s.y *= inv; s.z *= inv; s.w *= inv;
        out4[(long)seg * D4 + t] = s;
    }
}

extern "C" void kernel_launch(void* const* d_in, const int* in_sizes, int n_in,
                              void* d_out, int out_size, void* d_ws, size_t ws_size,
                              hipStream_t stream)
{
    const float4* x4  = (const float4*)d_in[0];
    const int*    b32 = (const int*)d_in[1];
    float4*       out = (float4*)d_out;
    const long N = (long)in_sizes[1];

    const size_t BOUNDS_BYTES = 8192;                       // 1025 ints, padded/aligned
    const size_t PART_BYTES   = (size_t)NB * DDIM * 4;      // 2 MiB
    if (ws_size >= BOUNDS_BYTES + PART_BYTES) {
        int*    bounds = (int*)d_ws;
        float4* part   = (float4*)((char*)d_ws + BOUNDS_BYTES);
        bounds_kernel <<<NSEG / 256, 256, 0, stream>>>(b32, bounds, N);
        partial_kernel<<<NB,         256, 0, stream>>>(x4, bounds, part);
        combine_kernel<<<NSEG * D4 / 256, 256, 0, stream>>>(part, bounds, out);
    } else {
        seg_mean_kernel<<<NSEG, 256, 0, stream>>>(x4, b32, out, N);
    }
}

// Round 4
// 163.330 us; speedup vs baseline: 1.1678x; 1.1678x over previous
//
#include <hip/hip_runtime.h>

// Segment-mean pooling: x [N,128] fp32, batch [N] sorted int -> out [1024,128] fp32.
// 3-phase: A) bounds via binary search, B) partial sums with nontemporal
// (read-once) loads + software-pipelined prefetch, C) combine + divide.

#define NSEG  1024
#define DDIM  128
#define D4    32          // DDIM / 4 floats per float4
#define SPLIT 4
#define NB    (NSEG * SPLIT)

typedef float f32x4 __attribute__((ext_vector_type(4)));

__device__ __forceinline__ int bload(const int* __restrict__ b, long i, bool is64) {
    // int64 little-endian: value in even i32 word (values < 1024 => hi word 0)
    return is64 ? b[i << 1] : b[i];
}

__device__ __forceinline__ f32x4 ntload(const f32x4* __restrict__ p) {
    return __builtin_nontemporal_load(p);
}

// ---------- Phase A: bounds[s] = lower_bound(batch, s), bounds[NSEG] = N ----
__global__ __launch_bounds__(256) void bounds_kernel(
    const int* __restrict__ b32, int* __restrict__ bounds, long N)
{
    const int gid = blockIdx.x * 256 + threadIdx.x;   // [0, NSEG)
    const bool is64 = (b32[N - 1] == 0);
    if (gid == 0) bounds[0] = 0;
    const int v = gid + 1;                 // lower_bound(v), v in [1, NSEG]
    long lo = 0, hi = N;
    while (lo < hi) {
        long mid = (lo + hi) >> 1;
        if (bload(b32, mid, is64) < v) lo = mid + 1; else hi = mid;
    }
    bounds[v] = (int)lo;
}

// ---------- Phase B: partial sums, one block per (segment, quarter) ---------
__global__ __launch_bounds__(256) void partial_kernel(
    const f32x4* __restrict__ x4, const int* __restrict__ bounds,
    f32x4* __restrict__ part)
{
    const int bid = blockIdx.x;
    const int seg = bid >> 2;
    const int q   = bid & 3;
    const int t   = threadIdx.x;

    const int start = bounds[seg];
    const int len   = bounds[seg + 1] - start;
    const int p0 = start + (int)(((long)len * q)       >> 2);
    const int p1 = start + (int)(((long)len * (q + 1)) >> 2);

    const int c = t & 31;   // float4 column
    const int r = t >> 5;   // row offset within group of 8

    f32x4 a0 = 0.f, a1 = 0.f, a2 = 0.f, a3 = 0.f;

    int row = p0 + r;

    if (row + 24 < p1) {
        // software pipeline: n* hold the in-flight next group while we
        // accumulate the current one -> 8 nt-loads outstanding per wave
        f32x4 n0 = ntload(&x4[(long)(row     ) * D4 + c]);
        f32x4 n1 = ntload(&x4[(long)(row +  8) * D4 + c]);
        f32x4 n2 = ntload(&x4[(long)(row + 16) * D4 + c]);
        f32x4 n3 = ntload(&x4[(long)(row + 24) * D4 + c]);
        row += 32;
        for (; row + 24 < p1; row += 32) {
            f32x4 v0 = n0, v1 = n1, v2 = n2, v3 = n3;
            n0 = ntload(&x4[(long)(row     ) * D4 + c]);
            n1 = ntload(&x4[(long)(row +  8) * D4 + c]);
            n2 = ntload(&x4[(long)(row + 16) * D4 + c]);
            n3 = ntload(&x4[(long)(row + 24) * D4 + c]);
            a0 += v0; a1 += v1; a2 += v2; a3 += v3;
        }
        a0 += n0; a1 += n1; a2 += n2; a3 += n3;
    }
    for (; row < p1; row += 8) {
        a0 += ntload(&x4[(long)row * D4 + c]);
    }
    a0 += a1 + a2 + a3;

    __shared__ f32x4 red[256];
    red[t] = a0;
    __syncthreads();

    if (t < 32) {
        f32x4 s = red[t];
#pragma unroll
        for (int rr = 1; rr < 8; ++rr) s += red[t + 32 * rr];
        part[(long)bid * D4 + t] = s;
    }
}

// ---------- Phase C: out[s][d] = (sum of 4 partials) / count ----------------
__global__ __launch_bounds__(256) void combine_kernel(
    const f32x4* __restrict__ part, const int* __restrict__ bounds,
    f32x4* __restrict__ out4)
{
    const int idx = blockIdx.x * 256 + threadIdx.x;   // [0, NSEG*32)
    const int s = idx >> 5;
    const int c = idx & 31;

    f32x4 a = part[(long)(s * 4 + 0) * D4 + c]
            + part[(long)(s * 4 + 1) * D4 + c]
            + part[(long)(s * 4 + 2) * D4 + c]
            + part[(long)(s * 4 + 3) * D4 + c];

    const int cnt = bounds[s + 1] - bounds[s];
    const float inv = (cnt > 0) ? 1.0f / (float)cnt : 0.0f;
    a *= inv;
    out4[idx] = a;
}

// ---------- Fallback: single-kernel path (small ws) --------------------------
__global__ __launch_bounds__(256) void seg_mean_kernel(
    const f32x4* __restrict__ x4, const int* __restrict__ b32,
    f32x4* __restrict__ out4, long N)
{
    const int seg = blockIdx.x;
    const int t   = threadIdx.x;
    const bool is64 = (b32[N - 1] == 0);

    long lo = 0, hi = N;
    while (lo < hi) { long mid = (lo + hi) >> 1; if (bload(b32, mid, is64) < seg) lo = mid + 1; else hi = mid; }
    const long start = lo;
    hi = N;
    while (lo < hi) { long mid = (lo + hi) >> 1; if (bload(b32, mid, is64) <= seg) lo = mid + 1; else hi = mid; }
    const long end = lo;
    const long cnt = end - start;

    const int c = t & 31, r = t >> 5;
    f32x4 a0 = 0.f, a1 = 0.f, a2 = 0.f, a3 = 0.f;

    long row = start + r;
    for (; row + 24 < end; row += 32) {
        a0 += ntload(&x4[(row      ) * D4 + c]);
        a1 += ntload(&x4[(row +  8 ) * D4 + c]);
        a2 += ntload(&x4[(row + 16 ) * D4 + c]);
        a3 += ntload(&x4[(row + 24 ) * D4 + c]);
    }
    for (; row < end; row += 8) {
        a0 += ntload(&x4[row * D4 + c]);
    }
    a0 += a1 + a2 + a3;

    __shared__ f32x4 red[256];
    red[t] = a0;
    __syncthreads();

    if (t < 32) {
        f32x4 s = red[t];
#pragma unroll
        for (int rr = 1; rr < 8; ++rr) s += red[t + 32 * rr];
        const float inv = (cnt > 0) ? 1.0f / (float)cnt : 0.0f;
        s *= inv;
        out4[(long)seg * D4 + t] = s;
    }
}

extern "C" void kernel_launch(void* const* d_in, const int* in_sizes, int n_in,
                              void* d_out, int out_size, void* d_ws, size_t ws_size,
                              hipStream_t stream)
{
    const f32x4* x4  = (const f32x4*)d_in[0];
    const int*   b32 = (const int*)d_in[1];
    f32x4*       out = (f32x4*)d_out;
    const long N = (long)in_sizes[1];

    const size_t BOUNDS_BYTES = 8192;
    const size_t PART_BYTES   = (size_t)NB * DDIM * 4;      // 2 MiB
    if (ws_size >= BOUNDS_BYTES + PART_BYTES) {
        int*   bounds = (int*)d_ws;
        f32x4* part   = (f32x4*)((char*)d_ws + BOUNDS_BYTES);
        bounds_kernel <<<NSEG / 256, 256, 0, stream>>>(b32, bounds, N);
        partial_kernel<<<NB,         256, 0, stream>>>(x4, bounds, part);
        combine_kernel<<<NSEG * D4 / 256, 256, 0, stream>>>(part, bounds, out);
    } else {
        seg_mean_kernel<<<NSEG, 256, 0, stream>>>(x4, b32, out, N);
    }
}